// Round 1
// baseline (378.042 us; speedup 1.0000x reference)
//
#include <hip/hip_runtime.h>

// Problem constants (from reference setup_inputs)
#define S 4096
#define B 32
#define H 512

// ---------------------------------------------------------------------------
// Kernel 1: v[b,h] = sum_g hidden[b,g] * W[g,h]   (v = hidden @ W, [B,H])
// grid (B, 2), 256 threads: each thread owns one output column h.
// W[g*H + h] reads are coalesced across threads (consecutive h).
// bias term hidden[b]·attn_b is a per-b constant -> cancels in softmax, skipped.
// ---------------------------------------------------------------------------
__global__ __launch_bounds__(256) void proj_kernel(
    const float* __restrict__ hidden,
    const float* __restrict__ W,
    float* __restrict__ v)
{
    __shared__ float sh[H];
    const int b = blockIdx.x;
    const int h = blockIdx.y * 256 + threadIdx.x;
    for (int g = threadIdx.x; g < H; g += 256)
        sh[g] = hidden[b * H + g];
    __syncthreads();

    float acc = 0.f;
#pragma unroll 16
    for (int g = 0; g < H; ++g)
        acc += sh[g] * W[g * H + h];
    v[b * H + h] = acc;
}

// ---------------------------------------------------------------------------
// Kernel 2: scoresT[b*S + s] = enc[s,b,:] . v[b,:]
// One wave (64 lanes) per (s,b) pair; 4 waves per 256-thread block.
// enc flat index: (s*B + b)*H + h  ->  p*H + h with p = s*B+b.
// Each lane: two coalesced float4 loads (lane and lane+64 of the 128-float4
// row), 8 FMAs, then 6-step shuffle reduction.
// ---------------------------------------------------------------------------
__global__ __launch_bounds__(256) void score_kernel(
    const float4* __restrict__ enc4,
    const float4* __restrict__ v4,
    float* __restrict__ scoresT)
{
    const int wave = threadIdx.x >> 6;
    const int lane = threadIdx.x & 63;
    const int p = blockIdx.x * 4 + wave;   // p = s*B + b
    const int b = p & (B - 1);
    const int s = p >> 5;                  // B == 32

    const float4* e = enc4 + (size_t)p * (H / 4);
    const float4* w = v4 + (size_t)b * (H / 4);

    float4 e0 = e[lane];
    float4 e1 = e[64 + lane];
    float4 w0 = w[lane];
    float4 w1 = w[64 + lane];

    float d = e0.x * w0.x + e0.y * w0.y + e0.z * w0.z + e0.w * w0.w
            + e1.x * w1.x + e1.y * w1.y + e1.z * w1.z + e1.w * w1.w;

#pragma unroll
    for (int off = 32; off >= 1; off >>= 1)
        d += __shfl_down(d, off, 64);

    if (lane == 0)
        scoresT[(size_t)b * S + s] = d;
}

// ---------------------------------------------------------------------------
// Kernel 3: out[b, s] = softmax over s of scoresT[b, :]
// 32 blocks (one per b), 256 threads, 16 elements/thread held in registers.
// ---------------------------------------------------------------------------
__global__ __launch_bounds__(256) void softmax_kernel(
    const float* __restrict__ scoresT,
    float* __restrict__ out)
{
    __shared__ float redm[4];
    __shared__ float reds[4];

    const int b = blockIdx.x;
    const int t = threadIdx.x;
    const int lane = t & 63;
    const int wv = t >> 6;
    const float* row = scoresT + (size_t)b * S;

    float x[16];
    float m = -INFINITY;
#pragma unroll
    for (int i = 0; i < 16; ++i) {
        x[i] = row[t + i * 256];
        m = fmaxf(m, x[i]);
    }
#pragma unroll
    for (int off = 32; off >= 1; off >>= 1)
        m = fmaxf(m, __shfl_down(m, off, 64));
    if (lane == 0) redm[wv] = m;
    __syncthreads();
    m = fmaxf(fmaxf(redm[0], redm[1]), fmaxf(redm[2], redm[3]));

    float sum = 0.f;
#pragma unroll
    for (int i = 0; i < 16; ++i) {
        x[i] = __expf(x[i] - m);
        sum += x[i];
    }
#pragma unroll
    for (int off = 32; off >= 1; off >>= 1)
        sum += __shfl_down(sum, off, 64);
    if (lane == 0) reds[wv] = sum;
    __syncthreads();
    sum = reds[0] + reds[1] + reds[2] + reds[3];

    const float inv = 1.f / sum;
#pragma unroll
    for (int i = 0; i < 16; ++i)
        out[(size_t)b * S + t + i * 256] = x[i] * inv;
}

// ---------------------------------------------------------------------------
extern "C" void kernel_launch(void* const* d_in, const int* in_sizes, int n_in,
                              void* d_out, int out_size, void* d_ws, size_t ws_size,
                              hipStream_t stream)
{
    const float* hidden = (const float*)d_in[0];   // [B, H]
    const float* enc    = (const float*)d_in[1];   // [S, B, H]
    const float* W      = (const float*)d_in[2];   // [H, H]  (g, h)
    // d_in[3] = attn_b: per-b constant under softmax -> unused.

    float* out     = (float*)d_out;                // [B, 1, S] -> B*S floats
    float* v       = (float*)d_ws;                 // [B, H]   (64 KB)
    float* scoresT = v + B * H;                    // [B, S]   (512 KB)

    proj_kernel<<<dim3(B, 2), 256, 0, stream>>>(hidden, W, v);
    score_kernel<<<(S * B) / 4, 256, 0, stream>>>(
        (const float4*)enc, (const float4*)v, scoresT);
    softmax_kernel<<<B, 256, 0, stream>>>(scoresT, out);
}

// Round 3
// 356.990 us; speedup vs baseline: 1.0590x; 1.0590x over previous
//
#include <hip/hip_runtime.h>

// Problem constants (from reference setup_inputs)
#define S 4096
#define B 32
#define H 512

// Native Clang vector type: accepted by __builtin_nontemporal_load
// (HIP's float4 is a class and is rejected). Same 16-B layout.
typedef float nfloat4 __attribute__((ext_vector_type(4)));

// ---------------------------------------------------------------------------
// Kernel 1: v[b,h] = sum_g hidden[b,g] * W[g,h]   (v = hidden @ W, [B,H])
// grid (B, 2), 256 threads; thread owns one output column h; W reads coalesced.
// bias term hidden[b]·attn_b is a per-b constant -> cancels in softmax, skipped.
// ~3 us, not a bottleneck.
// ---------------------------------------------------------------------------
__global__ __launch_bounds__(256) void proj_kernel(
    const float* __restrict__ hidden,
    const float* __restrict__ W,
    float* __restrict__ v)
{
    __shared__ float sh[H];
    const int b = blockIdx.x;
    const int h = blockIdx.y * 256 + threadIdx.x;
    for (int g = threadIdx.x; g < H; g += 256)
        sh[g] = hidden[b * H + g];
    __syncthreads();

    float acc = 0.f;
#pragma unroll 16
    for (int g = 0; g < H; ++g)
        acc += sh[g] * W[g * H + h];
    v[b * H + h] = acc;
}

// ---------------------------------------------------------------------------
// Kernel 2: scoresT[b*S + s] = enc[s,b,:] . v[b,:]
// One wave per TWO s-rows of the SAME b: v fragment loaded once per wave
// (halves v L2 traffic), two independent shuffle chains (DS-pipe ILP),
// coalesced float2 store of the adjacent (s0, s0+1) results.
// enc loads nontemporal: pure stream, keep L2 for v.
// q in [0, S*B/2): b = q & 31, s0 = (q >> 5)*2.
// ---------------------------------------------------------------------------
__global__ __launch_bounds__(256) void score_kernel(
    const nfloat4* __restrict__ enc4,
    const nfloat4* __restrict__ v4,
    float* __restrict__ scoresT)
{
    const int wave = threadIdx.x >> 6;
    const int lane = threadIdx.x & 63;
    const int q = blockIdx.x * 4 + wave;
    const int b = q & (B - 1);
    const int s0 = (q >> 5) << 1;

    const nfloat4* e0p = enc4 + (size_t)(s0 * B + b) * (H / 4);
    const nfloat4* e1p = e0p + (size_t)B * (H / 4);    // row (s0+1, b)
    const nfloat4* w   = v4 + (size_t)b * (H / 4);

    nfloat4 wa = w[lane];
    nfloat4 wb = w[64 + lane];
    nfloat4 a0 = __builtin_nontemporal_load(&e0p[lane]);
    nfloat4 a1 = __builtin_nontemporal_load(&e0p[64 + lane]);
    nfloat4 c0 = __builtin_nontemporal_load(&e1p[lane]);
    nfloat4 c1 = __builtin_nontemporal_load(&e1p[64 + lane]);

    float d0 = a0.x * wa.x + a0.y * wa.y + a0.z * wa.z + a0.w * wa.w
             + a1.x * wb.x + a1.y * wb.y + a1.z * wb.z + a1.w * wb.w;
    float d1 = c0.x * wa.x + c0.y * wa.y + c0.z * wa.z + c0.w * wa.w
             + c1.x * wb.x + c1.y * wb.y + c1.z * wb.z + c1.w * wb.w;

#pragma unroll
    for (int off = 32; off >= 1; off >>= 1) {
        d0 += __shfl_down(d0, off, 64);
        d1 += __shfl_down(d1, off, 64);
    }

    if (lane == 0) {
        float2 st;
        st.x = d0;
        st.y = d1;
        *(float2*)&scoresT[(size_t)b * S + s0] = st;
    }
}

// ---------------------------------------------------------------------------
// Kernel 3: out[b, :] = softmax(scoresT[b, :]) over S.
// 32 blocks x 1024 threads; exactly one float4 per thread (4096 = 1024*4).
// Two reduction trees (max, sum) via wave shuffle + 16-slot LDS.
// ---------------------------------------------------------------------------
__global__ __launch_bounds__(1024) void softmax_kernel(
    const float4* __restrict__ scoresT4,
    float4* __restrict__ out4)
{
    __shared__ float red[16];

    const int b = blockIdx.x;
    const int t = threadIdx.x;
    const int lane = t & 63;
    const int wv = t >> 6;

    float4 x = scoresT4[(size_t)b * (S / 4) + t];

    float m = fmaxf(fmaxf(x.x, x.y), fmaxf(x.z, x.w));
#pragma unroll
    for (int off = 32; off >= 1; off >>= 1)
        m = fmaxf(m, __shfl_down(m, off, 64));
    if (lane == 0) red[wv] = m;
    __syncthreads();
#pragma unroll
    for (int i = 0; i < 16; ++i)
        m = fmaxf(m, red[i]);

    float4 ex;
    ex.x = __expf(x.x - m);
    ex.y = __expf(x.y - m);
    ex.z = __expf(x.z - m);
    ex.w = __expf(x.w - m);
    float ssum = ex.x + ex.y + ex.z + ex.w;
#pragma unroll
    for (int off = 32; off >= 1; off >>= 1)
        ssum += __shfl_down(ssum, off, 64);
    __syncthreads();                 // everyone done reading red (max phase)
    if (lane == 0) red[wv] = ssum;
    __syncthreads();

    float tot = 0.f;
#pragma unroll
    for (int i = 0; i < 16; ++i)
        tot += red[i];

    const float inv = 1.f / tot;
    ex.x *= inv; ex.y *= inv; ex.z *= inv; ex.w *= inv;
    out4[(size_t)b * (S / 4) + t] = ex;
}

// ---------------------------------------------------------------------------
extern "C" void kernel_launch(void* const* d_in, const int* in_sizes, int n_in,
                              void* d_out, int out_size, void* d_ws, size_t ws_size,
                              hipStream_t stream)
{
    const float* hidden = (const float*)d_in[0];   // [B, H]
    const float* enc    = (const float*)d_in[1];   // [S, B, H]
    const float* W      = (const float*)d_in[2];   // [H, H]  (g, h)
    // d_in[3] = attn_b: per-b constant under softmax -> unused.

    float* out     = (float*)d_out;                // [B, 1, S] -> B*S floats
    float* v       = (float*)d_ws;                 // [B, H]   (64 KB)
    float* scoresT = v + B * H;                    // [B, S]   (512 KB)

    proj_kernel<<<dim3(B, 2), 256, 0, stream>>>(hidden, W, v);
    score_kernel<<<(S * B / 2) / 4, 256, 0, stream>>>(
        (const nfloat4*)enc, (const nfloat4*)v, scoresT);
    softmax_kernel<<<B, 1024, 0, stream>>>(
        (const float4*)scoresT, (float4*)out);
}